// Round 20
// baseline (100.728 us; speedup 1.0000x reference)
//
#include <hip/hip_runtime.h>
#include <stdint.h>

// A2aSparseMLP: B=1, S=2048, H=1024, I=1024, E=8, TOP_K=2, ALPHA=1.702, LIMIT=7
// Round 20: prep latency fix. pre1/pre2 load their full tile into registers
// FIRST (16 independent float4 loads in flight), then write LDS. Everything
// else identical to round 19 (100.5 us).

#define Sd 2048
#define Hd 1024
#define Id 1024

typedef __bf16 bf16x8 __attribute__((ext_vector_type(8)));
typedef _Float16 f16x8 __attribute__((ext_vector_type(8)));
typedef float f32x4 __attribute__((ext_vector_type(4)));

__device__ __forceinline__ f32x4 mfma_bf16(bf16x8 a, bf16x8 b, f32x4 c) {
  return __builtin_amdgcn_mfma_f32_16x16x32_bf16(a, b, c, 0, 0, 0);
}

__device__ __forceinline__ void gload16(const __bf16* g, __bf16* l) {
  __builtin_amdgcn_global_load_lds(
      (const __attribute__((address_space(1))) unsigned int*)g,
      (__attribute__((address_space(3))) unsigned int*)l, 16, 0, 0);
}

__device__ __forceinline__ unsigned int packbf(float lo, float hi) {
  __bf16 a = (__bf16)lo, b = (__bf16)hi;
  return (unsigned int)__builtin_bit_cast(unsigned short, a) |
         ((unsigned int)__builtin_bit_cast(unsigned short, b) << 16);
}

// ------ prep (interleaved roles): b&3==0 router, 1/2 pre1, 3 pre2 ------
__global__ __launch_bounds__(256) void k_prep(
    const float* __restrict__ x, const float* __restrict__ rw,
    const float* __restrict__ rb, float* __restrict__ scores,
    float* __restrict__ topw, int* __restrict__ eid, __bf16* __restrict__ xb,
    const float* __restrict__ wgu, __bf16* __restrict__ w1f,
    const float* __restrict__ wdn, __bf16* __restrict__ w2f) {
  __shared__ unsigned int Ls[16][16][34];
  const int blk = blockIdx.x;
  const int role = blk & 3;
  const int tid = threadIdx.x;
  const int lane = tid & 63;
  if (role == 0) {
    // ---------------- router (idx 0..511) ----------------
    const int rblk = blk >> 2;
    const int t = rblk * 4 + (tid >> 6);
    float acc[8];
#pragma unroll
    for (int e = 0; e < 8; ++e) acc[e] = 0.f;
    const float* xr = x + (size_t)t * Hd;
    unsigned int* xbo = (unsigned int*)(xb + (size_t)t * Hd);
#pragma unroll
    for (int j = 0; j < 8; ++j) {
      int h = j * 128 + lane * 2;
      float2 xv = *(const float2*)(xr + h);
      xbo[h >> 1] = packbf(xv.x, xv.y);
      const float4* wp = (const float4*)(rw + h * 8);
      float4 a0 = wp[0], a1 = wp[1], b0 = wp[2], b1 = wp[3];
      acc[0] += xv.x * a0.x; acc[1] += xv.x * a0.y;
      acc[2] += xv.x * a0.z; acc[3] += xv.x * a0.w;
      acc[4] += xv.x * a1.x; acc[5] += xv.x * a1.y;
      acc[6] += xv.x * a1.z; acc[7] += xv.x * a1.w;
      acc[0] += xv.y * b0.x; acc[1] += xv.y * b0.y;
      acc[2] += xv.y * b0.z; acc[3] += xv.y * b0.w;
      acc[4] += xv.y * b1.x; acc[5] += xv.y * b1.y;
      acc[6] += xv.y * b1.z; acc[7] += xv.y * b1.w;
    }
#pragma unroll
    for (int m = 32; m >= 1; m >>= 1) {
#pragma unroll
      for (int e = 0; e < 8; ++e) acc[e] += __shfl_xor(acc[e], m, 64);
    }
    if (lane == 0) {
      float lg[8];
#pragma unroll
      for (int e = 0; e < 8; ++e) lg[e] = acc[e] + rb[e];
      int i0 = 0; float v0 = lg[0];
#pragma unroll
      for (int e = 1; e < 8; ++e) if (lg[e] > v0) { v0 = lg[e]; i0 = e; }
      int i1 = -1; float v1 = -3.4e38f;
#pragma unroll
      for (int e = 0; e < 8; ++e) if (e != i0 && lg[e] > v1) { v1 = lg[e]; i1 = e; }
      float e1 = __expf(v1 - v0);
      float s = 1.f + e1;
      float w0 = 1.f / s, w1v = e1 / s;
#pragma unroll
      for (int e = 0; e < 8; ++e)
        scores[t * 8 + e] = (e == i0) ? w0 : ((e == i1) ? w1v : 0.f);
      topw[t * 2] = w0;
      topw[t * 2 + 1] = w1v;
      eid[t] = i0 | (i1 << 4);
    }
  } else if (role != 3) {
    // ---------------- pre1 (idx 0..1023): wgu -> w1f frag order ----------------
    const int b = (blk >> 2) * 2 + (role - 1);
    const int nt = b & 7, kt = (b >> 3) & 15, e = b >> 7;
    const int w = tid >> 6;
    const float* src = wgu + (size_t)e * (1024 * 2048) +
                       (size_t)(kt * 64 + w * 16) * 2048 + nt * 256;
    // phase 1: ALL 16 loads issued back-to-back into registers
    float4 fa[8], fb[8];
#pragma unroll
    for (int rp = 0; rp < 8; ++rp) {
      fa[rp] = *(const float4*)(src + (size_t)(rp * 2) * 2048 + lane * 4);
      fb[rp] = *(const float4*)(src + (size_t)(rp * 2 + 1) * 2048 + lane * 4);
    }
    // phase 2: LDS transpose writes
    const int i0 = lane * 2;
    const int c0 = i0 & 15, u0 = (i0 >> 4) * 2;
    const int c1 = (i0 + 1) & 15, u1 = ((i0 + 1) >> 4) * 2;
#pragma unroll
    for (int rp = 0; rp < 8; ++rp) {
      int r = w * 8 + rp;
      Ls[u0][c0][r] = packbf(fa[rp].x, fb[rp].x);
      Ls[u0 + 1][c0][r] = packbf(fa[rp].y, fb[rp].y);
      Ls[u1][c1][r] = packbf(fa[rp].z, fb[rp].z);
      Ls[u1 + 1][c1][r] = packbf(fa[rp].w, fb[rp].w);
    }
    __syncthreads();
    const int khi = lane >> 4, c = lane & 15;
#pragma unroll
    for (int uu = 0; uu < 8; ++uu) {
      int ul = w * 8 + uu, vu = ul >> 1, k32l = ul & 1;
      const unsigned int* p = &Ls[vu][c][k32l * 16 + khi * 4];
      uint2 q0 = *(const uint2*)p;
      uint2 q1 = *(const uint2*)(p + 2);
      int itg = nt * 8 + (vu >> 1), vf = vu & 1;
      size_t row = ((size_t)(e * 64 + itg) * 2 + vf) * 32 + (kt * 2 + k32l);
      uint4 o = {q0.x, q0.y, q1.x, q1.y};
      *(uint4*)(w1f + row * 512 + lane * 8) = o;
    }
  } else {
    // ---------------- pre2 (idx 0..511): wdn -> w2f frag order ----------------
    const int b = blk >> 2;
    const int nt = b & 3, kt = (b >> 2) & 15, e = b >> 6;
    const int w = tid >> 6;
    const float* src = wdn + (size_t)e * (1024 * 1024) +
                       (size_t)(kt * 64 + w * 16) * 1024 + nt * 256;
    float4 fa[8], fb[8];
#pragma unroll
    for (int rp = 0; rp < 8; ++rp) {
      fa[rp] = *(const float4*)(src + (size_t)(rp * 2) * 1024 + lane * 4);
      fb[rp] = *(const float4*)(src + (size_t)(rp * 2 + 1) * 1024 + lane * 4);
    }
#pragma unroll
    for (int rp = 0; rp < 8; ++rp) {
      int r = w * 8 + rp;
      float va[4] = {fa[rp].x, fa[rp].y, fa[rp].z, fa[rp].w};
      float vb[4] = {fb[rp].x, fb[rp].y, fb[rp].z, fb[rp].w};
#pragma unroll
      for (int q = 0; q < 4; ++q) {
        int cl = lane * 4 + q;
        Ls[cl >> 4][cl & 15][r] = packbf(va[q], vb[q]);
      }
    }
    __syncthreads();
    const int khi = lane >> 4, c = lane & 15;
#pragma unroll
    for (int uu = 0; uu < 8; ++uu) {
      int ul = w * 8 + uu, Fl = ul >> 1, k32l = ul & 1;
      const unsigned int* p = &Ls[Fl][c][k32l * 16 + khi * 4];
      uint2 q0 = *(const uint2*)p;
      uint2 q1 = *(const uint2*)(p + 2);
      size_t row = (size_t)(e * 64 + nt * 16 + Fl) * 32 + (kt * 2 + k32l);
      uint4 o = {q0.x, q0.y, q1.x, q1.y};
      *(uint4*)(w2f + row * 512 + lane * 8) = o;
    }
  }
}

// ------ assign: single block, LDS counters (no global atomics) ------
__global__ __launch_bounds__(256) void k_assign(
    const int* __restrict__ eid, int* __restrict__ cnt,
    int* __restrict__ assign, int* __restrict__ tokmap) {
  __shared__ int lcnt[8];
  const int tid = threadIdx.x;
  if (tid < 8) lcnt[tid] = 0;
  __syncthreads();
  for (int t = tid; t < 2048; t += 256) {
    int v = eid[t];
    int i0 = v & 15, i1 = v >> 4;
    int s0 = atomicAdd(&lcnt[i0], 1);
    assign[i0 * 2048 + s0] = t * 2;
    tokmap[t * 2] = (i0 << 11) | s0;
    int s1 = atomicAdd(&lcnt[i1], 1);
    assign[i1 * 2048 + s1] = t * 2 + 1;
    tokmap[t * 2 + 1] = (i1 << 11) | s1;
  }
  __syncthreads();
  if (tid < 8) cnt[tid] = lcnt[tid];
}

// ------ gather: xb rows -> xg in MFMA-A fragment order (once) ------
__global__ __launch_bounds__(256) void k_gather(
    const __bf16* __restrict__ xb, const int* __restrict__ cnt,
    const int* __restrict__ assign, __bf16* __restrict__ xg) {
  const int u = blockIdx.x;
  int acc = 0, myE = -1, myU0 = 0, nE = 0;
#pragma unroll
  for (int q = 0; q < 8; ++q) {
    int units = ((cnt[q] + 255) >> 8) * 16;
    if (u >= acc && u < acc + units) { myE = q; myU0 = acc; nE = cnt[q]; }
    acc += units;
  }
  if (myE < 0) return;
  const int lane = threadIdx.x & 63;
  const int wv = threadIdx.x >> 6;
  const int row = lane & 15, koff = (lane >> 4) * 8;
  const int slot = (u - myU0) * 16 + row;
  const bool valid = slot < nE;
  int tok = 0;
  if (valid) tok = assign[myE * 2048 + slot] >> 1;
  const __bf16* src = xb + (size_t)tok * Hd + koff;
#pragma unroll
  for (int s = 0; s < 8; ++s) {
    int k32 = wv + 4 * s;
    bf16x8 v;
#pragma unroll
    for (int j = 0; j < 8; ++j) v[j] = (__bf16)0.f;
    if (valid) v = *(const bf16x8*)(src + k32 * 32);
    *(bf16x8*)(xg + (((size_t)u * 32 + k32) * 64 + lane) * 8) = v;
  }
}

// ------ GEMM1: B-resident 32-col x full-K panel (128KB), e8 x it32 x ms2 ------
__global__ __launch_bounds__(512, 2) void k_gemm1(
    const __bf16* __restrict__ xg, const __bf16* __restrict__ w1f,
    const float* __restrict__ gub, const int* __restrict__ cnt,
    __bf16* __restrict__ abuf) {
  const int e = blockIdx.x & 7;
  const int r = blockIdx.x >> 3;
  const int it = r & 31;   // 32 real cols per block
  const int ms = r >> 5;   // 0..1
  const int n = cnt[e];
  if (n <= 0) return;
  const int nmt = (n + 255) >> 8;
  if (ms >= nmt) return;
  __shared__ __align__(16) __bf16 Bs[4][32][512];  // 128 KB
  __shared__ __align__(16) __bf16 Ts[256][48];     // 24 KB
  const int tid = threadIdx.x;
  const int lane = tid & 63;
  const int wv = tid >> 6;

#pragma unroll
  for (int s = 0; s < 16; ++s) {
    int idx = s * 512 + tid;
    int v = idx >> 11, k = (idx >> 6) & 31, l = idx & 63;
    size_t rowv = (size_t)(e * 64 + it * 2 + (v >> 1)) * 2 + (v & 1);
    gload16(w1f + (rowv * 32 + k) * 512 + l * 8, &Bs[v][k][l * 8]);
  }
  float bgv[2], buv[2];
#pragma unroll
  for (int p = 0; p < 2; ++p) {
    const int col = it * 32 + p * 16 + (lane & 15);
    bgv[p] = gub[e * 2048 + 2 * col];
    buv[p] = gub[e * 2048 + 2 * col + 1];
  }
  int eb = 0;
#pragma unroll
  for (int q = 0; q < 8; ++q) eb += (q < e) ? (((cnt[q] + 255) >> 8) << 8) : 0;
  const int u0 = eb >> 4;

  for (int mt = ms; mt < nmt; mt += 2) {
    __syncthreads();  // first iter: panel gloads drained; later: Ts WAR
    const __bf16* ap0 =
        xg + ((size_t)(u0 + mt * 16 + 2 * wv) * 32) * 512 + lane * 8;
    const __bf16* ap1 = ap0 + (size_t)32 * 512;
    f32x4 acc[2][4];
#pragma unroll
    for (int a = 0; a < 2; ++a)
#pragma unroll
      for (int b = 0; b < 4; ++b) acc[a][b] = (f32x4){0.f, 0.f, 0.f, 0.f};
    bf16x8 pf[4][2];
#pragma unroll
    for (int d = 0; d < 4; ++d) {
      pf[d][0] = *(const bf16x8*)(ap0 + d * 512);
      pf[d][1] = *(const bf16x8*)(ap1 + d * 512);
    }
#pragma unroll 4
    for (int ks = 0; ks < 28; ++ks) {
      bf16x8 b[4];
#pragma unroll
      for (int v = 0; v < 4; ++v) b[v] = *(const bf16x8*)&Bs[v][ks][lane * 8];
#pragma unroll
      for (int v = 0; v < 4; ++v) {
        acc[0][v] = mfma_bf16(pf[ks & 3][0], b[v], acc[0][v]);
        acc[1][v] = mfma_bf16(pf[ks & 3][1], b[v], acc[1][v]);
      }
      pf[ks & 3][0] = *(const bf16x8*)(ap0 + (ks + 4) * 512);
      pf[ks & 3][1] = *(const bf16x8*)(ap1 + (ks + 4) * 512);
    }
#pragma unroll
    for (int ks = 28; ks < 32; ++ks) {
      bf16x8 b[4];
#pragma unroll
      for (int v = 0; v < 4; ++v) b[v] = *(const bf16x8*)&Bs[v][ks][lane * 8];
#pragma unroll
      for (int v = 0; v < 4; ++v) {
        acc[0][v] = mfma_bf16(pf[ks & 3][0], b[v], acc[0][v]);
        acc[1][v] = mfma_bf16(pf[ks & 3][1], b[v], acc[1][v]);
      }
    }
#pragma unroll
    for (int itgl = 0; itgl < 2; ++itgl) {
      const int colL = itgl * 16 + (lane & 15);
#pragma unroll
      for (int mi = 0; mi < 2; ++mi) {
        f32x4 ag = acc[mi][itgl * 2];
        f32x4 au = acc[mi][itgl * 2 + 1];
#pragma unroll
        for (int rr = 0; rr < 4; ++rr) {
          int row = wv * 32 + mi * 16 + (lane >> 4) * 4 + rr;
          float g = fminf(ag[rr] + bgv[itgl], 7.f);
          float u = fminf(fmaxf(au[rr] + buv[itgl], -7.f), 7.f);
          float sg = 1.f / (1.f + __expf(-1.702f * g));
          Ts[row][colL] = (__bf16)((u + 1.f) * (g * sg));
        }
      }
    }
    __syncthreads();  // Ts ready
#pragma unroll
    for (int h2 = 0; h2 < 2; ++h2) {
      int idx = h2 * 512 + tid;
      int sbl = idx >> 6, l = idx & 63;
      bf16x8 v = *(const bf16x8*)&Ts[sbl * 16 + (l & 15)][(l >> 4) * 8];
      size_t o = ((size_t)(u0 + mt * 16 + sbl) * 32 + it) * 512 + l * 8;
      *(bf16x8*)(abuf + o) = v;
    }
  }
}

// ------ GEMM2: B-resident 64-col panel (128KB), e8 x ht16 x ms4 ------
__global__ __launch_bounds__(512, 2) void k_gemm2(
    const __bf16* __restrict__ abuf, const __bf16* __restrict__ w2f,
    const float* __restrict__ dnb, const int* __restrict__ cnt,
    const int* __restrict__ assign, const float* __restrict__ topw,
    _Float16* __restrict__ dbuf) {
  const int e = blockIdx.x & 7;
  const int r = blockIdx.x >> 3;
  const int ht = r & 15;   // 64 h cols per block
  const int ms = r >> 4;   // 0..3
  const int n = cnt[e];
  if (n <= 0) return;
  const int nmt = (n + 255) >> 8;
  if (ms >= nmt) return;   // skip panel stage entirely when no work
  __shared__ __align__(16) __bf16 Bs[4][32][512];  // 128 KB
  __shared__ float wgt[256];
  const int tid = threadIdx.x;
  const int lane = tid & 63;
  const int wv = tid >> 6;

#pragma unroll
  for (int s = 0; s < 16; ++s) {
    int idx = s * 512 + tid;
    int v = idx >> 11, k = (idx >> 6) & 31, l = idx & 63;
    size_t rowv = (size_t)(e * 64 + ht * 4 + v);
    gload16(w2f + (rowv * 32 + k) * 512 + l * 8, &Bs[v][k][l * 8]);
  }
  int eb = 0;
#pragma unroll
  for (int q = 0; q < 8; ++q) eb += (q < e) ? (((cnt[q] + 255) >> 8) << 8) : 0;
  const int u0 = eb >> 4;

  for (int mt = ms; mt < nmt; mt += 4) {
    __syncthreads();  // prev iter's wgt reads done
    if (tid < 256) {
      int slot = mt * 256 + tid;
      int en = (slot < n) ? assign[e * 2048 + slot] : -1;
      wgt[tid] = (en >= 0) ? topw[en] : 0.f;
    }
    __syncthreads();  // publish (first iter also drains panel gloads)
    const __bf16* ab0 =
        abuf + ((size_t)(u0 + mt * 16 + 2 * wv) * 32) * 512 + lane * 8;
    const __bf16* ab1 = ab0 + (size_t)32 * 512;
    f32x4 acc[2][4];
#pragma unroll
    for (int a = 0; a < 2; ++a)
#pragma unroll
      for (int b = 0; b < 4; ++b) acc[a][b] = (f32x4){0.f, 0.f, 0.f, 0.f};
    bf16x8 pf[4][2];
#pragma unroll
    for (int d = 0; d < 4; ++d) {
      pf[d][0] = *(const bf16x8*)(ab0 + d * 512);
      pf[d][1] = *(const bf16x8*)(ab1 + d * 512);
    }
#pragma unroll 4
    for (int ks = 0; ks < 28; ++ks) {
      bf16x8 b[4];
#pragma unroll
      for (int v = 0; v < 4; ++v) b[v] = *(const bf16x8*)&Bs[v][ks][lane * 8];
#pragma unroll
      for (int v = 0; v < 4; ++v) {
        acc[0][v] = mfma_bf16(pf[ks & 3][0], b[v], acc[0][v]);
        acc[1][v] = mfma_bf16(pf[ks & 3][1], b[v], acc[1][v]);
      }
      pf[ks & 3][0] = *(const bf16x8*)(ab0 + (ks + 4) * 512);
      pf[ks & 3][1] = *(const bf16x8*)(ab1 + (ks + 4) * 512);
    }
#pragma unroll
    for (int ks = 28; ks < 32; ++ks) {
      bf16x8 b[4];
#pragma unroll
      for (int v = 0; v < 4; ++v) b[v] = *(const bf16x8*)&Bs[v][ks][lane * 8];
#pragma unroll
      for (int v = 0; v < 4; ++v) {
        acc[0][v] = mfma_bf16(pf[ks & 3][0], b[v], acc[0][v]);
        acc[1][v] = mfma_bf16(pf[ks & 3][1], b[v], acc[1][v]);
      }
    }
#pragma unroll
    for (int v = 0; v < 4; ++v) {
      const int nn = ht * 64 + v * 16 + (lane & 15);
      const float bias = dnb[e * 1024 + nn];
#pragma unroll
      for (int mi = 0; mi < 2; ++mi) {
#pragma unroll
        for (int rr = 0; rr < 4; ++rr) {
          int row = wv * 32 + mi * 16 + (lane >> 4) * 4 + rr;
          int slot = eb + mt * 256 + row;
          dbuf[(size_t)slot * 1024 + nn] =
              (_Float16)(wgt[row] * (acc[mi][v][rr] + bias));
        }
      }
    }
  }
}

// ------ combine: out[t] = dbuf[s0] + dbuf[s1] (coalesced) ------
__global__ __launch_bounds__(256) void k_combine(
    const _Float16* __restrict__ dbuf, const int* __restrict__ tokmap,
    const int* __restrict__ cnt, float* __restrict__ out) {
  const int t = blockIdx.x * 4 + (threadIdx.x >> 6);
  const int lane = threadIdx.x & 63;
  int v0 = tokmap[t * 2], v1 = tokmap[t * 2 + 1];
  int e0 = v0 >> 11, e1 = v1 >> 11;
  int b0 = 0, b1 = 0, acc = 0;
#pragma unroll
  for (int q = 0; q < 8; ++q) {
    if (q == e0) b0 = acc;
    if (q == e1) b1 = acc;
    acc += ((cnt[q] + 255) >> 8) << 8;
  }
  const _Float16* r0 = dbuf + (size_t)(b0 + (v0 & 2047)) * 1024 + lane * 16;
  const _Float16* r1 = dbuf + (size_t)(b1 + (v1 & 2047)) * 1024 + lane * 16;
  float* o = out + (size_t)t * 1024 + lane * 16;
#pragma unroll
  for (int h = 0; h < 2; ++h) {
    f16x8 a = *(const f16x8*)(r0 + h * 8);
    f16x8 b = *(const f16x8*)(r1 + h * 8);
    float4 o0, o1;
    o0.x = (float)a[0] + (float)b[0];
    o0.y = (float)a[1] + (float)b[1];
    o0.z = (float)a[2] + (float)b[2];
    o0.w = (float)a[3] + (float)b[3];
    o1.x = (float)a[4] + (float)b[4];
    o1.y = (float)a[5] + (float)b[5];
    o1.z = (float)a[6] + (float)b[6];
    o1.w = (float)a[7] + (float)b[7];
    *(float4*)(o + h * 8) = o0;
    *(float4*)(o + h * 8 + 4) = o1;
  }
}

extern "C" void kernel_launch(void* const* d_in, const int* in_sizes, int n_in,
                              void* d_out, int out_size, void* d_ws, size_t ws_size,
                              hipStream_t stream) {
  const float* x   = (const float*)d_in[0];
  const float* rw  = (const float*)d_in[1];
  const float* rb  = (const float*)d_in[2];
  const float* wgu = (const float*)d_in[3];
  const float* gub = (const float*)d_in[4];
  const float* wdn = (const float*)d_in[5];
  const float* dnb = (const float*)d_in[6];
  float* out = (float*)d_out;
  float* scores = out + (size_t)Sd * Hd;

  char* ws = (char*)d_ws;
  int* cnt     = (int*)ws;                              // 32 B
  int* assign  = (int*)(ws + 256);                      // 64 KiB
  float* topw  = (float*)(ws + 256 + 65536);            // 16 KiB
  int* tokmap  = (int*)(ws + 256 + 65536 + 16384);      // 16 KiB
  int* eid     = (int*)(ws + 256 + 65536 + 32768);      // 8 KiB
  __bf16* xg   = (__bf16*)(ws + ((size_t)1 << 20));     // frag A, <=12.6 MiB
  __bf16* abuf = (__bf16*)(ws + ((size_t)15 << 20));    // frag act, <=12.6 MiB
  __bf16* xb   = (__bf16*)(ws + ((size_t)28 << 20));    // 4 MiB
  __bf16* w1f  = (__bf16*)(ws + ((size_t)33 << 20));    // 32 MiB
  __bf16* w2f  = (__bf16*)(ws + ((size_t)66 << 20));    // 16 MiB (no aliasing)
  _Float16* dbuf = (_Float16*)(ws + ((size_t)83 << 20)); // <=12.6 MiB

  k_prep<<<2048, 256, 0, stream>>>(x, rw, rb, scores, topw, eid, xb,
                                   wgu, w1f, wdn, w2f);
  k_assign<<<1, 256, 0, stream>>>(eid, cnt, assign, tokmap);
  k_gather<<<384, 256, 0, stream>>>(xb, cnt, assign, xg);
  k_gemm1<<<512, 512, 0, stream>>>(xg, w1f, gub, cnt, abuf);
  k_gemm2<<<512, 512, 0, stream>>>(abuf, w2f, dnb, cnt, assign, topw, dbuf);
  k_combine<<<512, 256, 0, stream>>>(dbuf, tokmap, cnt, out);
}

// Round 21
// 100.165 us; speedup vs baseline: 1.0056x; 1.0056x over previous
//
#include <hip/hip_runtime.h>
#include <stdint.h>

// A2aSparseMLP: B=1, S=2048, H=1024, I=1024, E=8, TOP_K=2, ALPHA=1.702, LIMIT=7
// Round 21: prep loads forced via inline-asm global_load_dwordx4 (compiler
// provably re-sank the C-level batch: VGPR=60 < 64-reg payload). 16 loads in
// flight per thread, then vmcnt(0)+sched_barrier, then LDS transpose.
// Everything else identical to round 19/20 (100.5 us).

#define Sd 2048
#define Hd 1024
#define Id 1024

typedef __bf16 bf16x8 __attribute__((ext_vector_type(8)));
typedef _Float16 f16x8 __attribute__((ext_vector_type(8)));
typedef float f32x4 __attribute__((ext_vector_type(4)));

__device__ __forceinline__ f32x4 mfma_bf16(bf16x8 a, bf16x8 b, f32x4 c) {
  return __builtin_amdgcn_mfma_f32_16x16x32_bf16(a, b, c, 0, 0, 0);
}

__device__ __forceinline__ void gload16(const __bf16* g, __bf16* l) {
  __builtin_amdgcn_global_load_lds(
      (const __attribute__((address_space(1))) unsigned int*)g,
      (__attribute__((address_space(3))) unsigned int*)l, 16, 0, 0);
}

// inline-asm 16B load: cannot be sunk/merged by the scheduler.
__device__ __forceinline__ uint4 aload4(const float* addr) {
  uint4 r;
  asm volatile("global_load_dwordx4 %0, %1, off" : "=v"(r) : "v"(addr));
  return r;
}

__device__ __forceinline__ unsigned int packbf(float lo, float hi) {
  __bf16 a = (__bf16)lo, b = (__bf16)hi;
  return (unsigned int)__builtin_bit_cast(unsigned short, a) |
         ((unsigned int)__builtin_bit_cast(unsigned short, b) << 16);
}

__device__ __forceinline__ unsigned int packbf_u(unsigned int lo, unsigned int hi) {
  __bf16 a = (__bf16)__builtin_bit_cast(float, lo);
  __bf16 b = (__bf16)__builtin_bit_cast(float, hi);
  return (unsigned int)__builtin_bit_cast(unsigned short, a) |
         ((unsigned int)__builtin_bit_cast(unsigned short, b) << 16);
}

// ------ prep (interleaved roles): b&3==0 router, 1/2 pre1, 3 pre2 ------
__global__ __launch_bounds__(256) void k_prep(
    const float* __restrict__ x, const float* __restrict__ rw,
    const float* __restrict__ rb, float* __restrict__ scores,
    float* __restrict__ topw, int* __restrict__ eid, __bf16* __restrict__ xb,
    const float* __restrict__ wgu, __bf16* __restrict__ w1f,
    const float* __restrict__ wdn, __bf16* __restrict__ w2f) {
  __shared__ unsigned int Ls[16][16][34];
  const int blk = blockIdx.x;
  const int role = blk & 3;
  const int tid = threadIdx.x;
  const int lane = tid & 63;
  if (role == 0) {
    // ---------------- router (idx 0..511) ----------------
    const int rblk = blk >> 2;
    const int t = rblk * 4 + (tid >> 6);
    float acc[8];
#pragma unroll
    for (int e = 0; e < 8; ++e) acc[e] = 0.f;
    const float* xr = x + (size_t)t * Hd;
    unsigned int* xbo = (unsigned int*)(xb + (size_t)t * Hd);
#pragma unroll
    for (int j = 0; j < 8; ++j) {
      int h = j * 128 + lane * 2;
      float2 xv = *(const float2*)(xr + h);
      xbo[h >> 1] = packbf(xv.x, xv.y);
      const float4* wp = (const float4*)(rw + h * 8);
      float4 a0 = wp[0], a1 = wp[1], b0 = wp[2], b1 = wp[3];
      acc[0] += xv.x * a0.x; acc[1] += xv.x * a0.y;
      acc[2] += xv.x * a0.z; acc[3] += xv.x * a0.w;
      acc[4] += xv.x * a1.x; acc[5] += xv.x * a1.y;
      acc[6] += xv.x * a1.z; acc[7] += xv.x * a1.w;
      acc[0] += xv.y * b0.x; acc[1] += xv.y * b0.y;
      acc[2] += xv.y * b0.z; acc[3] += xv.y * b0.w;
      acc[4] += xv.y * b1.x; acc[5] += xv.y * b1.y;
      acc[6] += xv.y * b1.z; acc[7] += xv.y * b1.w;
    }
#pragma unroll
    for (int m = 32; m >= 1; m >>= 1) {
#pragma unroll
      for (int e = 0; e < 8; ++e) acc[e] += __shfl_xor(acc[e], m, 64);
    }
    if (lane == 0) {
      float lg[8];
#pragma unroll
      for (int e = 0; e < 8; ++e) lg[e] = acc[e] + rb[e];
      int i0 = 0; float v0 = lg[0];
#pragma unroll
      for (int e = 1; e < 8; ++e) if (lg[e] > v0) { v0 = lg[e]; i0 = e; }
      int i1 = -1; float v1 = -3.4e38f;
#pragma unroll
      for (int e = 0; e < 8; ++e) if (e != i0 && lg[e] > v1) { v1 = lg[e]; i1 = e; }
      float e1 = __expf(v1 - v0);
      float s = 1.f + e1;
      float w0 = 1.f / s, w1v = e1 / s;
#pragma unroll
      for (int e = 0; e < 8; ++e)
        scores[t * 8 + e] = (e == i0) ? w0 : ((e == i1) ? w1v : 0.f);
      topw[t * 2] = w0;
      topw[t * 2 + 1] = w1v;
      eid[t] = i0 | (i1 << 4);
    }
  } else if (role != 3) {
    // ---------------- pre1 (idx 0..1023): wgu -> w1f frag order ----------------
    const int b = (blk >> 2) * 2 + (role - 1);
    const int nt = b & 7, kt = (b >> 3) & 15, e = b >> 7;
    const int w = tid >> 6;
    const float* src = wgu + (size_t)e * (1024 * 2048) +
                       (size_t)(kt * 64 + w * 16) * 2048 + nt * 256;
    // phase 1: ALL 16 loads forced in flight (asm, cannot be sunk)
    uint4 fa[8], fb[8];
#pragma unroll
    for (int rp = 0; rp < 8; ++rp) {
      fa[rp] = aload4(src + (size_t)(rp * 2) * 2048 + lane * 4);
      fb[rp] = aload4(src + (size_t)(rp * 2 + 1) * 2048 + lane * 4);
    }
    asm volatile("s_waitcnt vmcnt(0)" ::: "memory");
    __builtin_amdgcn_sched_barrier(0);
    // phase 2: LDS transpose writes
    const int i0 = lane * 2;
    const int c0 = i0 & 15, u0 = (i0 >> 4) * 2;
    const int c1 = (i0 + 1) & 15, u1 = ((i0 + 1) >> 4) * 2;
#pragma unroll
    for (int rp = 0; rp < 8; ++rp) {
      int r = w * 8 + rp;
      Ls[u0][c0][r] = packbf_u(fa[rp].x, fb[rp].x);
      Ls[u0 + 1][c0][r] = packbf_u(fa[rp].y, fb[rp].y);
      Ls[u1][c1][r] = packbf_u(fa[rp].z, fb[rp].z);
      Ls[u1 + 1][c1][r] = packbf_u(fa[rp].w, fb[rp].w);
    }
    __syncthreads();
    const int khi = lane >> 4, c = lane & 15;
#pragma unroll
    for (int uu = 0; uu < 8; ++uu) {
      int ul = w * 8 + uu, vu = ul >> 1, k32l = ul & 1;
      const unsigned int* p = &Ls[vu][c][k32l * 16 + khi * 4];
      uint2 q0 = *(const uint2*)p;
      uint2 q1 = *(const uint2*)(p + 2);
      int itg = nt * 8 + (vu >> 1), vf = vu & 1;
      size_t row = ((size_t)(e * 64 + itg) * 2 + vf) * 32 + (kt * 2 + k32l);
      uint4 o = {q0.x, q0.y, q1.x, q1.y};
      *(uint4*)(w1f + row * 512 + lane * 8) = o;
    }
  } else {
    // ---------------- pre2 (idx 0..511): wdn -> w2f frag order ----------------
    const int b = blk >> 2;
    const int nt = b & 3, kt = (b >> 2) & 15, e = b >> 6;
    const int w = tid >> 6;
    const float* src = wdn + (size_t)e * (1024 * 1024) +
                       (size_t)(kt * 64 + w * 16) * 1024 + nt * 256;
    uint4 fa[8], fb[8];
#pragma unroll
    for (int rp = 0; rp < 8; ++rp) {
      fa[rp] = aload4(src + (size_t)(rp * 2) * 1024 + lane * 4);
      fb[rp] = aload4(src + (size_t)(rp * 2 + 1) * 1024 + lane * 4);
    }
    asm volatile("s_waitcnt vmcnt(0)" ::: "memory");
    __builtin_amdgcn_sched_barrier(0);
#pragma unroll
    for (int rp = 0; rp < 8; ++rp) {
      int r = w * 8 + rp;
      unsigned int va[4] = {fa[rp].x, fa[rp].y, fa[rp].z, fa[rp].w};
      unsigned int vb[4] = {fb[rp].x, fb[rp].y, fb[rp].z, fb[rp].w};
#pragma unroll
      for (int q = 0; q < 4; ++q) {
        int cl = lane * 4 + q;
        Ls[cl >> 4][cl & 15][r] = packbf_u(va[q], vb[q]);
      }
    }
    __syncthreads();
    const int khi = lane >> 4, c = lane & 15;
#pragma unroll
    for (int uu = 0; uu < 8; ++uu) {
      int ul = w * 8 + uu, Fl = ul >> 1, k32l = ul & 1;
      const unsigned int* p = &Ls[Fl][c][k32l * 16 + khi * 4];
      uint2 q0 = *(const uint2*)p;
      uint2 q1 = *(const uint2*)(p + 2);
      size_t row = (size_t)(e * 64 + nt * 16 + Fl) * 32 + (kt * 2 + k32l);
      uint4 o = {q0.x, q0.y, q1.x, q1.y};
      *(uint4*)(w2f + row * 512 + lane * 8) = o;
    }
  }
}

// ------ assign: single block, LDS counters (no global atomics) ------
__global__ __launch_bounds__(256) void k_assign(
    const int* __restrict__ eid, int* __restrict__ cnt,
    int* __restrict__ assign, int* __restrict__ tokmap) {
  __shared__ int lcnt[8];
  const int tid = threadIdx.x;
  if (tid < 8) lcnt[tid] = 0;
  __syncthreads();
  for (int t = tid; t < 2048; t += 256) {
    int v = eid[t];
    int i0 = v & 15, i1 = v >> 4;
    int s0 = atomicAdd(&lcnt[i0], 1);
    assign[i0 * 2048 + s0] = t * 2;
    tokmap[t * 2] = (i0 << 11) | s0;
    int s1 = atomicAdd(&lcnt[i1], 1);
    assign[i1 * 2048 + s1] = t * 2 + 1;
    tokmap[t * 2 + 1] = (i1 << 11) | s1;
  }
  __syncthreads();
  if (tid < 8) cnt[tid] = lcnt[tid];
}

// ------ gather: xb rows -> xg in MFMA-A fragment order (once) ------
__global__ __launch_bounds__(256) void k_gather(
    const __bf16* __restrict__ xb, const int* __restrict__ cnt,
    const int* __restrict__ assign, __bf16* __restrict__ xg) {
  const int u = blockIdx.x;
  int acc = 0, myE = -1, myU0 = 0, nE = 0;
#pragma unroll
  for (int q = 0; q < 8; ++q) {
    int units = ((cnt[q] + 255) >> 8) * 16;
    if (u >= acc && u < acc + units) { myE = q; myU0 = acc; nE = cnt[q]; }
    acc += units;
  }
  if (myE < 0) return;
  const int lane = threadIdx.x & 63;
  const int wv = threadIdx.x >> 6;
  const int row = lane & 15, koff = (lane >> 4) * 8;
  const int slot = (u - myU0) * 16 + row;
  const bool valid = slot < nE;
  int tok = 0;
  if (valid) tok = assign[myE * 2048 + slot] >> 1;
  const __bf16* src = xb + (size_t)tok * Hd + koff;
#pragma unroll
  for (int s = 0; s < 8; ++s) {
    int k32 = wv + 4 * s;
    bf16x8 v;
#pragma unroll
    for (int j = 0; j < 8; ++j) v[j] = (__bf16)0.f;
    if (valid) v = *(const bf16x8*)(src + k32 * 32);
    *(bf16x8*)(xg + (((size_t)u * 32 + k32) * 64 + lane) * 8) = v;
  }
}

// ------ GEMM1: B-resident 32-col x full-K panel (128KB), e8 x it32 x ms2 ------
__global__ __launch_bounds__(512, 2) void k_gemm1(
    const __bf16* __restrict__ xg, const __bf16* __restrict__ w1f,
    const float* __restrict__ gub, const int* __restrict__ cnt,
    __bf16* __restrict__ abuf) {
  const int e = blockIdx.x & 7;
  const int r = blockIdx.x >> 3;
  const int it = r & 31;   // 32 real cols per block
  const int ms = r >> 5;   // 0..1
  const int n = cnt[e];
  if (n <= 0) return;
  const int nmt = (n + 255) >> 8;
  if (ms >= nmt) return;
  __shared__ __align__(16) __bf16 Bs[4][32][512];  // 128 KB
  __shared__ __align__(16) __bf16 Ts[256][48];     // 24 KB
  const int tid = threadIdx.x;
  const int lane = tid & 63;
  const int wv = tid >> 6;

#pragma unroll
  for (int s = 0; s < 16; ++s) {
    int idx = s * 512 + tid;
    int v = idx >> 11, k = (idx >> 6) & 31, l = idx & 63;
    size_t rowv = (size_t)(e * 64 + it * 2 + (v >> 1)) * 2 + (v & 1);
    gload16(w1f + (rowv * 32 + k) * 512 + l * 8, &Bs[v][k][l * 8]);
  }
  float bgv[2], buv[2];
#pragma unroll
  for (int p = 0; p < 2; ++p) {
    const int col = it * 32 + p * 16 + (lane & 15);
    bgv[p] = gub[e * 2048 + 2 * col];
    buv[p] = gub[e * 2048 + 2 * col + 1];
  }
  int eb = 0;
#pragma unroll
  for (int q = 0; q < 8; ++q) eb += (q < e) ? (((cnt[q] + 255) >> 8) << 8) : 0;
  const int u0 = eb >> 4;

  for (int mt = ms; mt < nmt; mt += 2) {
    __syncthreads();  // first iter: panel gloads drained; later: Ts WAR
    const __bf16* ap0 =
        xg + ((size_t)(u0 + mt * 16 + 2 * wv) * 32) * 512 + lane * 8;
    const __bf16* ap1 = ap0 + (size_t)32 * 512;
    f32x4 acc[2][4];
#pragma unroll
    for (int a = 0; a < 2; ++a)
#pragma unroll
      for (int b = 0; b < 4; ++b) acc[a][b] = (f32x4){0.f, 0.f, 0.f, 0.f};
    bf16x8 pf[4][2];
#pragma unroll
    for (int d = 0; d < 4; ++d) {
      pf[d][0] = *(const bf16x8*)(ap0 + d * 512);
      pf[d][1] = *(const bf16x8*)(ap1 + d * 512);
    }
#pragma unroll 4
    for (int ks = 0; ks < 28; ++ks) {
      bf16x8 b[4];
#pragma unroll
      for (int v = 0; v < 4; ++v) b[v] = *(const bf16x8*)&Bs[v][ks][lane * 8];
#pragma unroll
      for (int v = 0; v < 4; ++v) {
        acc[0][v] = mfma_bf16(pf[ks & 3][0], b[v], acc[0][v]);
        acc[1][v] = mfma_bf16(pf[ks & 3][1], b[v], acc[1][v]);
      }
      pf[ks & 3][0] = *(const bf16x8*)(ap0 + (ks + 4) * 512);
      pf[ks & 3][1] = *(const bf16x8*)(ap1 + (ks + 4) * 512);
    }
#pragma unroll
    for (int ks = 28; ks < 32; ++ks) {
      bf16x8 b[4];
#pragma unroll
      for (int v = 0; v < 4; ++v) b[v] = *(const bf16x8*)&Bs[v][ks][lane * 8];
#pragma unroll
      for (int v = 0; v < 4; ++v) {
        acc[0][v] = mfma_bf16(pf[ks & 3][0], b[v], acc[0][v]);
        acc[1][v] = mfma_bf16(pf[ks & 3][1], b[v], acc[1][v]);
      }
    }
#pragma unroll
    for (int itgl = 0; itgl < 2; ++itgl) {
      const int colL = itgl * 16 + (lane & 15);
#pragma unroll
      for (int mi = 0; mi < 2; ++mi) {
        f32x4 ag = acc[mi][itgl * 2];
        f32x4 au = acc[mi][itgl * 2 + 1];
#pragma unroll
        for (int rr = 0; rr < 4; ++rr) {
          int row = wv * 32 + mi * 16 + (lane >> 4) * 4 + rr;
          float g = fminf(ag[rr] + bgv[itgl], 7.f);
          float u = fminf(fmaxf(au[rr] + buv[itgl], -7.f), 7.f);
          float sg = 1.f / (1.f + __expf(-1.702f * g));
          Ts[row][colL] = (__bf16)((u + 1.f) * (g * sg));
        }
      }
    }
    __syncthreads();  // Ts ready
#pragma unroll
    for (int h2 = 0; h2 < 2; ++h2) {
      int idx = h2 * 512 + tid;
      int sbl = idx >> 6, l = idx & 63;
      bf16x8 v = *(const bf16x8*)&Ts[sbl * 16 + (l & 15)][(l >> 4) * 8];
      size_t o = ((size_t)(u0 + mt * 16 + sbl) * 32 + it) * 512 + l * 8;
      *(bf16x8*)(abuf + o) = v;
    }
  }
}

// ------ GEMM2: B-resident 64-col panel (128KB), e8 x ht16 x ms4 ------
__global__ __launch_bounds__(512, 2) void k_gemm2(
    const __bf16* __restrict__ abuf, const __bf16* __restrict__ w2f,
    const float* __restrict__ dnb, const int* __restrict__ cnt,
    const int* __restrict__ assign, const float* __restrict__ topw,
    _Float16* __restrict__ dbuf) {
  const int e = blockIdx.x & 7;
  const int r = blockIdx.x >> 3;
  const int ht = r & 15;   // 64 h cols per block
  const int ms = r >> 4;   // 0..3
  const int n = cnt[e];
  if (n <= 0) return;
  const int nmt = (n + 255) >> 8;
  if (ms >= nmt) return;   // skip panel stage entirely when no work
  __shared__ __align__(16) __bf16 Bs[4][32][512];  // 128 KB
  __shared__ float wgt[256];
  const int tid = threadIdx.x;
  const int lane = tid & 63;
  const int wv = tid >> 6;

#pragma unroll
  for (int s = 0; s < 16; ++s) {
    int idx = s * 512 + tid;
    int v = idx >> 11, k = (idx >> 6) & 31, l = idx & 63;
    size_t rowv = (size_t)(e * 64 + ht * 4 + v);
    gload16(w2f + (rowv * 32 + k) * 512 + l * 8, &Bs[v][k][l * 8]);
  }
  int eb = 0;
#pragma unroll
  for (int q = 0; q < 8; ++q) eb += (q < e) ? (((cnt[q] + 255) >> 8) << 8) : 0;
  const int u0 = eb >> 4;

  for (int mt = ms; mt < nmt; mt += 4) {
    __syncthreads();  // prev iter's wgt reads done
    if (tid < 256) {
      int slot = mt * 256 + tid;
      int en = (slot < n) ? assign[e * 2048 + slot] : -1;
      wgt[tid] = (en >= 0) ? topw[en] : 0.f;
    }
    __syncthreads();  // publish (first iter also drains panel gloads)
    const __bf16* ab0 =
        abuf + ((size_t)(u0 + mt * 16 + 2 * wv) * 32) * 512 + lane * 8;
    const __bf16* ab1 = ab0 + (size_t)32 * 512;
    f32x4 acc[2][4];
#pragma unroll
    for (int a = 0; a < 2; ++a)
#pragma unroll
      for (int b = 0; b < 4; ++b) acc[a][b] = (f32x4){0.f, 0.f, 0.f, 0.f};
    bf16x8 pf[4][2];
#pragma unroll
    for (int d = 0; d < 4; ++d) {
      pf[d][0] = *(const bf16x8*)(ab0 + d * 512);
      pf[d][1] = *(const bf16x8*)(ab1 + d * 512);
    }
#pragma unroll 4
    for (int ks = 0; ks < 28; ++ks) {
      bf16x8 b[4];
#pragma unroll
      for (int v = 0; v < 4; ++v) b[v] = *(const bf16x8*)&Bs[v][ks][lane * 8];
#pragma unroll
      for (int v = 0; v < 4; ++v) {
        acc[0][v] = mfma_bf16(pf[ks & 3][0], b[v], acc[0][v]);
        acc[1][v] = mfma_bf16(pf[ks & 3][1], b[v], acc[1][v]);
      }
      pf[ks & 3][0] = *(const bf16x8*)(ab0 + (ks + 4) * 512);
      pf[ks & 3][1] = *(const bf16x8*)(ab1 + (ks + 4) * 512);
    }
#pragma unroll
    for (int ks = 28; ks < 32; ++ks) {
      bf16x8 b[4];
#pragma unroll
      for (int v = 0; v < 4; ++v) b[v] = *(const bf16x8*)&Bs[v][ks][lane * 8];
#pragma unroll
      for (int v = 0; v < 4; ++v) {
        acc[0][v] = mfma_bf16(pf[ks & 3][0], b[v], acc[0][v]);
        acc[1][v] = mfma_bf16(pf[ks & 3][1], b[v], acc[1][v]);
      }
    }
#pragma unroll
    for (int v = 0; v < 4; ++v) {
      const int nn = ht * 64 + v * 16 + (lane & 15);
      const float bias = dnb[e * 1024 + nn];
#pragma unroll
      for (int mi = 0; mi < 2; ++mi) {
#pragma unroll
        for (int rr = 0; rr < 4; ++rr) {
          int row = wv * 32 + mi * 16 + (lane >> 4) * 4 + rr;
          int slot = eb + mt * 256 + row;
          dbuf[(size_t)slot * 1024 + nn] =
              (_Float16)(wgt[row] * (acc[mi][v][rr] + bias));
        }
      }
    }
  }
}

// ------ combine: out[t] = dbuf[s0] + dbuf[s1] (coalesced) ------
__global__ __launch_bounds__(256) void k_combine(
    const _Float16* __restrict__ dbuf, const int* __restrict__ tokmap,
    const int* __restrict__ cnt, float* __restrict__ out) {
  const int t = blockIdx.x * 4 + (threadIdx.x >> 6);
  const int lane = threadIdx.x & 63;
  int v0 = tokmap[t * 2], v1 = tokmap[t * 2 + 1];
  int e0 = v0 >> 11, e1 = v1 >> 11;
  int b0 = 0, b1 = 0, acc = 0;
#pragma unroll
  for (int q = 0; q < 8; ++q) {
    if (q == e0) b0 = acc;
    if (q == e1) b1 = acc;
    acc += ((cnt[q] + 255) >> 8) << 8;
  }
  const _Float16* r0 = dbuf + (size_t)(b0 + (v0 & 2047)) * 1024 + lane * 16;
  const _Float16* r1 = dbuf + (size_t)(b1 + (v1 & 2047)) * 1024 + lane * 16;
  float* o = out + (size_t)t * 1024 + lane * 16;
#pragma unroll
  for (int h = 0; h < 2; ++h) {
    f16x8 a = *(const f16x8*)(r0 + h * 8);
    f16x8 b = *(const f16x8*)(r1 + h * 8);
    float4 o0, o1;
    o0.x = (float)a[0] + (float)b[0];
    o0.y = (float)a[1] + (float)b[1];
    o0.z = (float)a[2] + (float)b[2];
    o0.w = (float)a[3] + (float)b[3];
    o1.x = (float)a[4] + (float)b[4];
    o1.y = (float)a[5] + (float)b[5];
    o1.z = (float)a[6] + (float)b[6];
    o1.w = (float)a[7] + (float)b[7];
    *(float4*)(o + h * 8) = o0;
    *(float4*)(o + h * 8 + 4) = o1;
  }
}

extern "C" void kernel_launch(void* const* d_in, const int* in_sizes, int n_in,
                              void* d_out, int out_size, void* d_ws, size_t ws_size,
                              hipStream_t stream) {
  const float* x   = (const float*)d_in[0];
  const float* rw  = (const float*)d_in[1];
  const float* rb  = (const float*)d_in[2];
  const float* wgu = (const float*)d_in[3];
  const float* gub = (const float*)d_in[4];
  const float* wdn = (const float*)d_in[5];
  const float* dnb = (const float*)d_in[6];
  float* out = (float*)d_out;
  float* scores = out + (size_t)Sd * Hd;

  char* ws = (char*)d_ws;
  int* cnt     = (int*)ws;                              // 32 B
  int* assign  = (int*)(ws + 256);                      // 64 KiB
  float* topw  = (float*)(ws + 256 + 65536);            // 16 KiB
  int* tokmap  = (int*)(ws + 256 + 65536 + 16384);      // 16 KiB
  int* eid     = (int*)(ws + 256 + 65536 + 32768);      // 8 KiB
  __bf16* xg   = (__bf16*)(ws + ((size_t)1 << 20));     // frag A, <=12.6 MiB
  __bf16* abuf = (__bf16*)(ws + ((size_t)15 << 20));    // frag act, <=12.6 MiB
  __bf16* xb   = (__bf16*)(ws + ((size_t)28 << 20));    // 4 MiB
  __bf16* w1f  = (__bf16*)(ws + ((size_t)33 << 20));    // 32 MiB
  __bf16* w2f  = (__bf16*)(ws + ((size_t)66 << 20));    // 16 MiB (no aliasing)
  _Float16* dbuf = (_Float16*)(ws + ((size_t)83 << 20)); // <=12.6 MiB

  k_prep<<<2048, 256, 0, stream>>>(x, rw, rb, scores, topw, eid, xb,
                                   wgu, w1f, wdn, w2f);
  k_assign<<<1, 256, 0, stream>>>(eid, cnt, assign, tokmap);
  k_gather<<<384, 256, 0, stream>>>(xb, cnt, assign, xg);
  k_gemm1<<<512, 512, 0, stream>>>(xg, w1f, gub, cnt, abuf);
  k_gemm2<<<512, 512, 0, stream>>>(abuf, w2f, dnb, cnt, assign, topw, dbuf);
  k_combine<<<512, 256, 0, stream>>>(dbuf, tokmap, cnt, out);
}